// Round 8
// baseline (221.439 us; speedup 1.0000x reference)
//
#include <hip/hip_runtime.h>

typedef _Float16 f16;
typedef f16 f16x8 __attribute__((ext_vector_type(8)));
typedef float f32x4 __attribute__((ext_vector_type(4)));

#define AS1 __attribute__((address_space(1)))
#define AS3 __attribute__((address_space(3)))

constexpr float kScale  = 7.896444077714954f;                       // 6 * 3^0.25
// q scale: SCALE / sqrt(512) * log2(e)  (scores produced directly in log2 units)
constexpr float kScaleQ = (float)(7.896444077714954 / 22.627416997969522 * 1.4426950408889634);

__device__ __forceinline__ void g2l16(const void* g, void* l) {
  __builtin_amdgcn_global_load_lds((const AS1 void*)g, (AS3 void*)l, 16, 0, 0);
}

// ---------------- LayerNorm: fp32 [rows,512] -> f16 ----------------
__global__ __launch_bounds__(256) void ln_kernel(
    const float* __restrict__ x, const float* __restrict__ g,
    const float* __restrict__ be, f16* __restrict__ out) {
  int row = blockIdx.x * 4 + (threadIdx.x >> 6);
  int lane = threadIdx.x & 63;
  const float* xr = x + (size_t)row * 512;
  float xa[8];
  *(float4*)&xa[0] = *(const float4*)(xr + lane * 8);
  *(float4*)&xa[4] = *(const float4*)(xr + lane * 8 + 4);
  float s = 0.f, q = 0.f;
#pragma unroll
  for (int i = 0; i < 8; ++i) { s += xa[i]; q += xa[i] * xa[i]; }
#pragma unroll
  for (int off = 32; off; off >>= 1) { s += __shfl_xor(s, off); q += __shfl_xor(q, off); }
  float mean = s * (1.f / 512.f);
  float var = q * (1.f / 512.f) - mean * mean;
  float rstd = rsqrtf(var + 1e-5f);
  float ga[8], ba[8];
  *(float4*)&ga[0] = *(const float4*)(g + lane * 8);
  *(float4*)&ga[4] = *(const float4*)(g + lane * 8 + 4);
  *(float4*)&ba[0] = *(const float4*)(be + lane * 8);
  *(float4*)&ba[4] = *(const float4*)(be + lane * 8 + 4);
  f16x8 o;
#pragma unroll
  for (int i = 0; i < 8; ++i) o[i] = (f16)((xa[i] - mean) * rstd * ga[i] + ba[i]);
  *(f16x8*)(out + (size_t)row * 512 + lane * 8) = o;
}

// ------------- transpose + f16 convert: out[Cc][R] = in[R][Cc]*scale -------------
__global__ __launch_bounds__(256) void transpose_cvt(
    const float* __restrict__ in, f16* __restrict__ out,
    int R, int Cc, long ibs, long obs, float scale) {
  __shared__ float t[32][33];
  int b = blockIdx.z;
  const float* im = in + (size_t)b * ibs;
  int c0 = blockIdx.x * 32, r0 = blockIdx.y * 32;
  int tx = threadIdx.x & 31, ty = threadIdx.x >> 5;
#pragma unroll
  for (int i = 0; i < 4; ++i) {
    int rr = ty + i * 8;
    t[rr][tx] = im[(size_t)(r0 + rr) * Cc + c0 + tx] * scale;
  }
  __syncthreads();
#pragma unroll
  for (int i = 0; i < 4; ++i) {
    int rr = ty + i * 8;
    out[(size_t)b * obs + (size_t)(c0 + rr) * R + r0 + tx] = (f16)t[tx][rr];
  }
}

// ------------- GEMM: C[M,N] = A[M,K] * Bt[N,K]^T, f16 in, fp32 acc -------------
// Double-buffered LDS, single barrier per K-step. W8: 512-thread blocks (8 waves,
// 2x4 wave grid, 64x32 per wave) for small-grid cases; else 256-thread (2x2 waves).
// MODE 0: qkv scatter (q,k -> [B,H,T,64]; v -> [B,H,D,T])
// MODE 1: out fp32 = acc + bias + res
// MODE 2: out f16  = relu(acc + bias)
// MODE 3: out fp32 = acc + bias*kScale + res
template <int MODE, bool W8>
__global__ __launch_bounds__(W8 ? 512 : 256) void gemm_bt(
    const f16* __restrict__ A, const f16* __restrict__ Bt,
    const float* __restrict__ bias, const float* __restrict__ res,
    float* __restrict__ outf, f16* __restrict__ outb,
    f16* __restrict__ qo, f16* __restrict__ ko, f16* __restrict__ vo,
    int N, int K) {
  __shared__ f16 lA[2][128 * 64], lB[2][128 * 64];
  constexpr int NF = W8 ? 2 : 4;          // N-fragments per wave
  constexpr int WCW = W8 ? 32 : 64;       // wave col width
  int tid = threadIdx.x;
  int lane = tid & 63, w = tid >> 6;
  int wr = W8 ? (w >> 2) : (w >> 1);
  int wc = W8 ? (w & 3) : (w & 1);
  int gq = lane >> 4, r = lane & 15;
  int m0 = blockIdx.x * 128, n0 = blockIdx.y * 128;
  size_t Kb = (size_t)K * 2;
  const char* Ab = (const char*)A + (size_t)m0 * Kb;
  const char* Bb = (const char*)Bt + (size_t)n0 * Kb;
  f32x4 acc[4][NF] = {};
  int srow = lane >> 3, sslot = lane & 7;
  auto stage = [&](int buf, int kt) {
#pragma unroll
    for (int i = 0; i < (W8 ? 2 : 4); ++i) {
      int chunk = i * (W8 ? 8 : 4) + w;
      int row = chunk * 8 + srow;
      int slot = sslot ^ (row & 7);
      g2l16(Ab + (size_t)row * Kb + kt * 2 + slot * 16, (char*)lA + buf * 16384 + chunk * 1024);
      g2l16(Bb + (size_t)row * Kb + kt * 2 + slot * 16, (char*)lB + buf * 16384 + chunk * 1024);
    }
  };
  stage(0, 0);
  int cur = 0;
  for (int kt = 0; kt < K; kt += 64) {
    __syncthreads();
    if (kt + 64 < K) stage(cur ^ 1, kt + 64);
    const char* bA = (const char*)lA + cur * 16384;
    const char* bB = (const char*)lB + cur * 16384;
    f16x8 af[4][2], bfr[NF][2];
#pragma unroll
    for (int f = 0; f < 4; ++f)
#pragma unroll
      for (int ks = 0; ks < 2; ++ks) {
        int ra = wr * 64 + f * 16 + r;
        af[f][ks] = *(const f16x8*)(bA + ra * 128 + (((ks * 4 + gq) ^ (ra & 7)) * 16));
      }
#pragma unroll
    for (int fn = 0; fn < NF; ++fn)
#pragma unroll
      for (int ks = 0; ks < 2; ++ks) {
        int rb = wc * WCW + fn * 16 + r;
        bfr[fn][ks] = *(const f16x8*)(bB + rb * 128 + (((ks * 4 + gq) ^ (rb & 7)) * 16));
      }
    __builtin_amdgcn_s_setprio(1);
#pragma unroll
    for (int fm = 0; fm < 4; ++fm)
#pragma unroll
      for (int fn = 0; fn < NF; ++fn)
#pragma unroll
        for (int ks = 0; ks < 2; ++ks)
          acc[fm][fn] = __builtin_amdgcn_mfma_f32_16x16x32_f16(af[fm][ks], bfr[fn][ks], acc[fm][fn], 0, 0, 0);
    __builtin_amdgcn_s_setprio(0);
    cur ^= 1;
  }
#pragma unroll
  for (int fm = 0; fm < 4; ++fm)
#pragma unroll
    for (int fn = 0; fn < NF; ++fn)
#pragma unroll
      for (int rg = 0; rg < 4; ++rg) {
        int row = m0 + wr * 64 + fm * 16 + gq * 4 + rg;
        int col = n0 + wc * WCW + fn * 16 + r;
        float v = acc[fm][fn][rg];
        if constexpr (MODE == 1) {
          outf[(size_t)row * N + col] = v + bias[col] + res[(size_t)row * N + col];
        } else if constexpr (MODE == 2) {
          outb[(size_t)row * N + col] = (f16)fmaxf(v + bias[col], 0.f);
        } else if constexpr (MODE == 3) {
          outf[(size_t)row * N + col] = v + bias[col] * kScale + res[(size_t)row * N + col];
        } else {
          int bb = row >> 11, t = row & 2047;
          int which = col >> 9, hd = col & 511, hh = hd >> 6, d = hd & 63;
          size_t bh = (size_t)bb * 8 + hh;
          if (which == 0)      qo[(bh * 2048 + t) * 64 + d] = (f16)v;
          else if (which == 1) ko[(bh * 2048 + t) * 64 + d] = (f16)v;
          else                 vo[(bh * 64 + d) * 2048 + t] = (f16)v;
        }
      }
}

// ------------- causal flash attention: 8 waves, split tile ownership -------------
// q,k:[B,H,T,64], v^T:[B,H,64,T]. Block (bh, p): waves 0-3 own q-tile p (16 rows
// each), waves 4-7 own q-tile 31-p. All 8 waves share the staged K/V stream
// (double-buffered, one barrier/iter); waves idle on kv tiles beyond their
// causal range. Scores in log2 units (log2e folded into q); exp2 softmax.
__global__ __launch_bounds__(512, 4) void attn_kernel(
    const f16* __restrict__ Q, const f16* __restrict__ K,
    const f16* __restrict__ Vt, f16* __restrict__ out) {
  __shared__ f16 lK[2][64 * 64], lV[2][64 * 64];
  __shared__ f16 lP[8][16 * 72];
  int tid = threadIdx.x, lane = tid & 63, w = tid >> 6;  // w: 0..7
  int gq = lane >> 4, r = lane & 15;
  int bh = blockIdx.x;   // 0..31
  int p = blockIdx.y;    // 0..15
  int qt = (w >> 2) ? (31 - p) : p;
  int q0 = qt * 64 + (w & 3) * 16;
  const char* Qb = (const char*)(Q + (size_t)bh * 2048 * 64);
  const char* Kb = (const char*)(K + (size_t)bh * 2048 * 64);
  const char* Vb = (const char*)(Vt + (size_t)bh * 64 * 2048);
  f16x8 qf[2];
#pragma unroll
  for (int ks = 0; ks < 2; ++ks)
    qf[ks] = *(const f16x8*)(Qb + (size_t)(q0 + r) * 128 + ks * 64 + gq * 16);
  f32x4 O[4] = {};
  float mrun[4], lrun[4];
#pragma unroll
  for (int rg = 0; rg < 4; ++rg) { mrun[rg] = -1e30f; lrun[rg] = 0.f; }
  int srow = lane >> 3, sslot = lane & 7;

  auto stage = [&](int buf, int kv) {
    int j0 = kv * 64;
    int row = w * 8 + srow;
    int slot = sslot ^ (row & 7);
    g2l16(Kb + (size_t)(j0 + row) * 128 + slot * 16, (char*)lK + buf * 8192 + w * 1024);
    g2l16(Vb + (size_t)row * 4096 + j0 * 2 + slot * 16, (char*)lV + buf * 8192 + w * 1024);
  };

  int nkv = 32 - p;
  stage(0, 0);
  int cur = 0;
  for (int kv = 0; kv < nkv; ++kv) {
    __syncthreads();
    if (kv + 1 < nkv) stage(cur ^ 1, kv + 1);
    if (kv <= qt) {
      int j0 = kv * 64;
      const char* bK = (const char*)lK + cur * 8192;
      const char* bV = (const char*)lV + cur * 8192;
      f16x8 kf[4][2], vf[4][2];
#pragma unroll
      for (int fc = 0; fc < 4; ++fc)
#pragma unroll
        for (int ks = 0; ks < 2; ++ks) {
          int rj = fc * 16 + r;
          kf[fc][ks] = *(const f16x8*)(bK + rj * 128 + (((ks * 4 + gq) ^ (rj & 7)) * 16));
          vf[fc][ks] = *(const f16x8*)(bV + rj * 128 + (((ks * 4 + gq) ^ (rj & 7)) * 16));
        }
      f32x4 s[4] = {};
#pragma unroll
      for (int ks = 0; ks < 2; ++ks)
#pragma unroll
        for (int fc = 0; fc < 4; ++fc)
          s[fc] = __builtin_amdgcn_mfma_f32_16x16x32_f16(qf[ks], kf[fc][ks], s[fc], 0, 0, 0);
      if (kv == qt) {  // diagonal tile
#pragma unroll
        for (int fc = 0; fc < 4; ++fc)
#pragma unroll
          for (int rg = 0; rg < 4; ++rg) {
            int t = q0 + gq * 4 + rg;
            int j = j0 + fc * 16 + r;
            if (j > t) s[fc][rg] = -1e30f;
          }
      }
#pragma unroll
      for (int rg = 0; rg < 4; ++rg) {
        float v = fmaxf(fmaxf(s[0][rg], s[1][rg]), fmaxf(s[2][rg], s[3][rg]));
        v = fmaxf(v, __shfl_xor(v, 1));
        v = fmaxf(v, __shfl_xor(v, 2));
        v = fmaxf(v, __shfl_xor(v, 4));
        v = fmaxf(v, __shfl_xor(v, 8));
        float mo = mrun[rg];
        float mn = fmaxf(mo, v);
        if (mn - mo > 11.5f) {  // defer-max (log2 units)
          float sc = exp2f(mo - mn);
          lrun[rg] *= sc;
#pragma unroll
          for (int fd = 0; fd < 4; ++fd) O[fd][rg] *= sc;
          mrun[rg] = mn;
        } else {
          mn = mo;
        }
        float ps = 0.f;
        int prow = gq * 4 + rg;
#pragma unroll
        for (int fc = 0; fc < 4; ++fc) {
          float pe = exp2f(s[fc][rg] - mn);
          ps += pe;
          lP[w][prow * 72 + fc * 16 + r] = (f16)pe;
        }
        ps += __shfl_xor(ps, 1);
        ps += __shfl_xor(ps, 2);
        ps += __shfl_xor(ps, 4);
        ps += __shfl_xor(ps, 8);
        lrun[rg] += ps;
      }
      f16x8 pf[2];
#pragma unroll
      for (int ks = 0; ks < 2; ++ks)
        pf[ks] = *(const f16x8*)((const char*)&lP[w][0] + r * 144 + ks * 64 + gq * 16);
#pragma unroll
      for (int fd = 0; fd < 4; ++fd)
#pragma unroll
        for (int ks = 0; ks < 2; ++ks)
          O[fd] = __builtin_amdgcn_mfma_f32_16x16x32_f16(pf[ks], vf[fd][ks], O[fd], 0, 0, 0);
    }
    cur ^= 1;
  }
  int bb = bh >> 3, hh = bh & 7;
#pragma unroll
  for (int fd = 0; fd < 4; ++fd)
#pragma unroll
    for (int rg = 0; rg < 4; ++rg) {
      int t = q0 + gq * 4 + rg;
      int d = fd * 16 + r;
      out[((size_t)bb * 2048 + t) * 512 + hh * 64 + d] = (f16)(O[fd][rg] / lrun[rg]);
    }
}

extern "C" void kernel_launch(void* const* d_in, const int* in_sizes, int n_in,
                              void* d_out, int out_size, void* d_ws, size_t ws_size,
                              hipStream_t stream) {
  (void)in_sizes; (void)n_in; (void)out_size; (void)ws_size;
  const float* x      = (const float*)d_in[0];
  const float* wq     = (const float*)d_in[1];
  const float* wk     = (const float*)d_in[2];
  const float* wv     = (const float*)d_in[3];
  const float* w_proj = (const float*)d_in[4];
  const float* b_proj = (const float*)d_in[5];
  const float* w1     = (const float*)d_in[6];
  const float* b1     = (const float*)d_in[7];
  const float* w2     = (const float*)d_in[8];
  const float* b2     = (const float*)d_in[9];
  const float* g1     = (const float*)d_in[10];
  const float* be1    = (const float*)d_in[11];
  const float* g2     = (const float*)d_in[12];
  const float* be2    = (const float*)d_in[13];
  float* outp = (float*)d_out;

  char* ws = (char*)d_ws;
  size_t off = 0;
  auto alloc = [&](size_t bytes) {
    char* p = ws + off;
    off += (bytes + 255) & ~(size_t)255;
    return p;
  };
  const size_t MC2 = (size_t)8192 * 512 * 2;   // 8.4 MB
  f16* x_ln  = (f16*)alloc(MC2);
  f16* qb    = (f16*)alloc(MC2);   // qb..attn (33.6 MB) reused as hbuf later
  f16* kb    = (f16*)alloc(MC2);
  f16* vb    = (f16*)alloc(MC2);
  f16* attn  = (f16*)alloc(MC2);
  float* x1  = (float*)alloc((size_t)8192 * 512 * 4);
  f16* Wqkv  = (f16*)alloc((size_t)1536 * 512 * 2);
  f16* Wp    = (f16*)alloc((size_t)512 * 512 * 2);
  f16* W1t   = (f16*)alloc((size_t)2048 * 512 * 2);
  f16* W2t   = (f16*)alloc((size_t)512 * 2048 * 2);
  f16* x1_ln = x_ln;
  f16* hbuf  = qb;  // 32 MB spans qb..attn

  // weights -> f16, transposed to [N][K]; scales folded (q gets 512^-0.5 * log2e)
  transpose_cvt<<<dim3(2, 16, 8), 256, 0, stream>>>(wq, Wqkv,                 512, 64, 512 * 64, 64 * 512, kScaleQ);
  transpose_cvt<<<dim3(2, 16, 8), 256, 0, stream>>>(wk, Wqkv + 512 * 512,     512, 64, 512 * 64, 64 * 512, kScale);
  transpose_cvt<<<dim3(2, 16, 8), 256, 0, stream>>>(wv, Wqkv + 2 * 512 * 512, 512, 64, 512 * 64, 64 * 512, kScale);
  transpose_cvt<<<dim3(16, 16, 1), 256, 0, stream>>>(w_proj, Wp, 512, 512, 0, 0, 1.f);
  transpose_cvt<<<dim3(64, 16, 1), 256, 0, stream>>>(w1, W1t, 512, 2048, 0, 0, 1.f);
  transpose_cvt<<<dim3(16, 64, 1), 256, 0, stream>>>(w2, W2t, 2048, 512, 0, 0, kScale);

  ln_kernel<<<2048, 256, 0, stream>>>(x, g1, be1, x_ln);
  gemm_bt<0, false><<<dim3(64, 12), 256, 0, stream>>>(x_ln, Wqkv, nullptr, nullptr, nullptr, nullptr,
                                                      qb, kb, vb, 1536, 512);
  attn_kernel<<<dim3(32, 16), 512, 0, stream>>>(qb, kb, vb, attn);
  gemm_bt<1, true><<<dim3(64, 4), 512, 0, stream>>>(attn, Wp, b_proj, x, x1, nullptr,
                                                    nullptr, nullptr, nullptr, 512, 512);
  ln_kernel<<<2048, 256, 0, stream>>>(x1, g2, be2, x1_ln);
  gemm_bt<2, false><<<dim3(64, 16), 256, 0, stream>>>(x1_ln, W1t, b1, nullptr, nullptr, hbuf,
                                                      nullptr, nullptr, nullptr, 2048, 512);
  gemm_bt<3, true><<<dim3(64, 4), 512, 0, stream>>>(hbuf, W2t, b2, x1, outp, nullptr,
                                                    nullptr, nullptr, nullptr, 512, 2048);
}

// Round 9
// 179.849 us; speedup vs baseline: 1.2312x; 1.2312x over previous
//
#include <hip/hip_runtime.h>

typedef _Float16 f16;
typedef f16 f16x4 __attribute__((ext_vector_type(4)));
typedef f16 f16x8 __attribute__((ext_vector_type(8)));
typedef float f32x4 __attribute__((ext_vector_type(4)));

#define AS1 __attribute__((address_space(1)))
#define AS3 __attribute__((address_space(3)))

constexpr float kScale  = 7.896444077714954f;                       // 6 * 3^0.25
// q scale: SCALE / sqrt(512) * log2(e)  (scores produced directly in log2 units)
constexpr float kScaleQ = (float)(7.896444077714954 / 22.627416997969522 * 1.4426950408889634);

__device__ __forceinline__ void g2l16(const void* g, void* l) {
  __builtin_amdgcn_global_load_lds((const AS1 void*)g, (AS3 void*)l, 16, 0, 0);
}

// ---------------- LayerNorm: fp32 [rows,512] -> f16 ----------------
__global__ __launch_bounds__(256) void ln_kernel(
    const float* __restrict__ x, const float* __restrict__ g,
    const float* __restrict__ be, f16* __restrict__ out) {
  int row = blockIdx.x * 4 + (threadIdx.x >> 6);
  int lane = threadIdx.x & 63;
  const float* xr = x + (size_t)row * 512;
  float xa[8];
  *(float4*)&xa[0] = *(const float4*)(xr + lane * 8);
  *(float4*)&xa[4] = *(const float4*)(xr + lane * 8 + 4);
  float s = 0.f, q = 0.f;
#pragma unroll
  for (int i = 0; i < 8; ++i) { s += xa[i]; q += xa[i] * xa[i]; }
#pragma unroll
  for (int off = 32; off; off >>= 1) { s += __shfl_xor(s, off); q += __shfl_xor(q, off); }
  float mean = s * (1.f / 512.f);
  float var = q * (1.f / 512.f) - mean * mean;
  float rstd = rsqrtf(var + 1e-5f);
  float ga[8], ba[8];
  *(float4*)&ga[0] = *(const float4*)(g + lane * 8);
  *(float4*)&ga[4] = *(const float4*)(g + lane * 8 + 4);
  *(float4*)&ba[0] = *(const float4*)(be + lane * 8);
  *(float4*)&ba[4] = *(const float4*)(be + lane * 8 + 4);
  f16x8 o;
#pragma unroll
  for (int i = 0; i < 8; ++i) o[i] = (f16)((xa[i] - mean) * rstd * ga[i] + ba[i]);
  *(f16x8*)(out + (size_t)row * 512 + lane * 8) = o;
}

// ------------- transpose + f16 convert: out[Cc][R] = in[R][Cc]*scale -------------
__global__ __launch_bounds__(256) void transpose_cvt(
    const float* __restrict__ in, f16* __restrict__ out,
    int R, int Cc, long ibs, long obs, float scale) {
  __shared__ float t[32][33];
  int b = blockIdx.z;
  const float* im = in + (size_t)b * ibs;
  int c0 = blockIdx.x * 32, r0 = blockIdx.y * 32;
  int tx = threadIdx.x & 31, ty = threadIdx.x >> 5;
#pragma unroll
  for (int i = 0; i < 4; ++i) {
    int rr = ty + i * 8;
    t[rr][tx] = im[(size_t)(r0 + rr) * Cc + c0 + tx] * scale;
  }
  __syncthreads();
#pragma unroll
  for (int i = 0; i < 4; ++i) {
    int rr = ty + i * 8;
    out[(size_t)b * obs + (size_t)(c0 + rr) * R + r0 + tx] = (f16)t[tx][rr];
  }
}

// ------------- GEMM: C[M,N] = A[M,K] * Bt[N,K]^T, f16 in, fp32 acc -------------
// Double-buffered LDS, single barrier per K-step. W8: 512-thread blocks (8 waves,
// 2x4 wave grid, 64x32 per wave) for small-grid cases; else 256-thread (2x2 waves).
// MODE 0: qkv scatter (q,k -> [B,H,T,64]; v -> [B,H,D,T])
// MODE 1: out fp32 = acc + bias + res
// MODE 2: out f16  = relu(acc + bias)
// MODE 3: out fp32 = acc + bias*kScale + res
template <int MODE, bool W8>
__global__ __launch_bounds__(W8 ? 512 : 256) void gemm_bt(
    const f16* __restrict__ A, const f16* __restrict__ Bt,
    const float* __restrict__ bias, const float* __restrict__ res,
    float* __restrict__ outf, f16* __restrict__ outb,
    f16* __restrict__ qo, f16* __restrict__ ko, f16* __restrict__ vo,
    int N, int K) {
  __shared__ f16 lA[2][128 * 64], lB[2][128 * 64];
  constexpr int NF = W8 ? 2 : 4;          // N-fragments per wave
  constexpr int WCW = W8 ? 32 : 64;       // wave col width
  int tid = threadIdx.x;
  int lane = tid & 63, w = tid >> 6;
  int wr = W8 ? (w >> 2) : (w >> 1);
  int wc = W8 ? (w & 3) : (w & 1);
  int gq = lane >> 4, r = lane & 15;
  int m0 = blockIdx.x * 128, n0 = blockIdx.y * 128;
  size_t Kb = (size_t)K * 2;
  const char* Ab = (const char*)A + (size_t)m0 * Kb;
  const char* Bb = (const char*)Bt + (size_t)n0 * Kb;
  f32x4 acc[4][NF] = {};
  int srow = lane >> 3, sslot = lane & 7;
  auto stage = [&](int buf, int kt) {
#pragma unroll
    for (int i = 0; i < (W8 ? 2 : 4); ++i) {
      int chunk = i * (W8 ? 8 : 4) + w;
      int row = chunk * 8 + srow;
      int slot = sslot ^ (row & 7);
      g2l16(Ab + (size_t)row * Kb + kt * 2 + slot * 16, (char*)lA + buf * 16384 + chunk * 1024);
      g2l16(Bb + (size_t)row * Kb + kt * 2 + slot * 16, (char*)lB + buf * 16384 + chunk * 1024);
    }
  };
  stage(0, 0);
  int cur = 0;
  for (int kt = 0; kt < K; kt += 64) {
    __syncthreads();
    if (kt + 64 < K) stage(cur ^ 1, kt + 64);
    const char* bA = (const char*)lA + cur * 16384;
    const char* bB = (const char*)lB + cur * 16384;
    f16x8 af[4][2], bfr[NF][2];
#pragma unroll
    for (int f = 0; f < 4; ++f)
#pragma unroll
      for (int ks = 0; ks < 2; ++ks) {
        int ra = wr * 64 + f * 16 + r;
        af[f][ks] = *(const f16x8*)(bA + ra * 128 + (((ks * 4 + gq) ^ (ra & 7)) * 16));
      }
#pragma unroll
    for (int fn = 0; fn < NF; ++fn)
#pragma unroll
      for (int ks = 0; ks < 2; ++ks) {
        int rb = wc * WCW + fn * 16 + r;
        bfr[fn][ks] = *(const f16x8*)(bB + rb * 128 + (((ks * 4 + gq) ^ (rb & 7)) * 16));
      }
    __builtin_amdgcn_s_setprio(1);
#pragma unroll
    for (int fm = 0; fm < 4; ++fm)
#pragma unroll
      for (int fn = 0; fn < NF; ++fn)
#pragma unroll
        for (int ks = 0; ks < 2; ++ks)
          acc[fm][fn] = __builtin_amdgcn_mfma_f32_16x16x32_f16(af[fm][ks], bfr[fn][ks], acc[fm][fn], 0, 0, 0);
    __builtin_amdgcn_s_setprio(0);
    cur ^= 1;
  }
#pragma unroll
  for (int fm = 0; fm < 4; ++fm)
#pragma unroll
    for (int fn = 0; fn < NF; ++fn)
#pragma unroll
      for (int rg = 0; rg < 4; ++rg) {
        int row = m0 + wr * 64 + fm * 16 + gq * 4 + rg;
        int col = n0 + wc * WCW + fn * 16 + r;
        float v = acc[fm][fn][rg];
        if constexpr (MODE == 1) {
          outf[(size_t)row * N + col] = v + bias[col] + res[(size_t)row * N + col];
        } else if constexpr (MODE == 2) {
          outb[(size_t)row * N + col] = (f16)fmaxf(v + bias[col], 0.f);
        } else if constexpr (MODE == 3) {
          outf[(size_t)row * N + col] = v + bias[col] * kScale + res[(size_t)row * N + col];
        } else {
          int bb = row >> 11, t = row & 2047;
          int which = col >> 9, hd = col & 511, hh = hd >> 6, d = hd & 63;
          size_t bh = (size_t)bb * 8 + hh;
          if (which == 0)      qo[(bh * 2048 + t) * 64 + d] = (f16)v;
          else if (which == 1) ko[(bh * 2048 + t) * 64 + d] = (f16)v;
          else                 vo[(bh * 64 + d) * 2048 + t] = (f16)v;
        }
      }
}

// ------------- causal flash attention, SWAPPED QK^T (lane-local softmax) -------------
// q,k:[B,H,T,64], v^T:[B,H,64,T]. Block (bh,p): 4 waves, tiles A=p and B=31-p
// (16 q-rows per wave per tile). Scores S^T = mfma(K, Q): lane holds 16 j-values
// for ONE q-row t = q0 + (lane&15) -> row max/sum = lane-local tree + 2 shuffles.
// PV: O^T = mfma(V^T, P). Scores in log2 units; exp2 softmax; defer-max.
__global__ __launch_bounds__(256) void attn_kernel(
    const f16* __restrict__ Q, const f16* __restrict__ K,
    const f16* __restrict__ Vt, f16* __restrict__ out) {
  __shared__ f16 lK[2][64 * 64], lV[2][64 * 64];
  __shared__ f16 lP[4][16 * 72];
  int tid = threadIdx.x, lane = tid & 63, w = tid >> 6;
  int gq = lane >> 4, r = lane & 15;
  int bh = blockIdx.x;   // 0..31
  int p = blockIdx.y;    // 0..15 -> tiles p and 31-p
  const char* Qb = (const char*)(Q + (size_t)bh * 2048 * 64);
  const char* Kb = (const char*)(K + (size_t)bh * 2048 * 64);
  const char* Vb = (const char*)(Vt + (size_t)bh * 64 * 2048);
  int q0A = p * 64 + w * 16;
  int q0B = (31 - p) * 64 + w * 16;
  f16x8 qfA[2], qfB[2];
#pragma unroll
  for (int ks = 0; ks < 2; ++ks) {
    qfA[ks] = *(const f16x8*)(Qb + (size_t)(q0A + r) * 128 + ks * 64 + gq * 16);
    qfB[ks] = *(const f16x8*)(Qb + (size_t)(q0B + r) * 128 + ks * 64 + gq * 16);
  }
  f32x4 OA[4] = {}, OB[4] = {};
  float mA = -1e30f, lA_ = 0.f, mB = -1e30f, lB_ = 0.f;
  int srow = lane >> 3, sslot = lane & 7;

  auto stage = [&](int buf, int kv) {
    int j0 = kv * 64;
#pragma unroll
    for (int i = 0; i < 2; ++i) {
      int chunk = i * 4 + w;
      int row = chunk * 8 + srow;
      int slot = sslot ^ (row & 7);
      g2l16(Kb + (size_t)(j0 + row) * 128 + slot * 16, (char*)lK + buf * 8192 + chunk * 1024);
      g2l16(Vb + (size_t)row * 4096 + j0 * 2 + slot * 16, (char*)lV + buf * 8192 + chunk * 1024);
    }
  };

  f16x8 vf[4][2];
  // s[fc][rg] holds S^T[j][t]: j = j0 + fc*16 + gq*4 + rg, t = q0 + r
  auto smpv = [&](f32x4 (&s)[4], float& m, float& l, f32x4 (&O)[4]) {
    float t0 = fmaxf(fmaxf(s[0][0], s[0][1]), fmaxf(s[0][2], s[0][3]));
    float t1 = fmaxf(fmaxf(s[1][0], s[1][1]), fmaxf(s[1][2], s[1][3]));
    float t2 = fmaxf(fmaxf(s[2][0], s[2][1]), fmaxf(s[2][2], s[2][3]));
    float t3 = fmaxf(fmaxf(s[3][0], s[3][1]), fmaxf(s[3][2], s[3][3]));
    float pmax = fmaxf(fmaxf(t0, t1), fmaxf(t2, t3));
    pmax = fmaxf(pmax, __shfl_xor(pmax, 16));
    pmax = fmaxf(pmax, __shfl_xor(pmax, 32));
    float mn = fmaxf(m, pmax);
    if (mn - m > 11.5f) {  // defer-max (log2 units)
      float sc = exp2f(m - mn);
      l *= sc;
#pragma unroll
      for (int fd = 0; fd < 4; ++fd) O[fd] *= sc;
      m = mn;
    } else {
      mn = m;
    }
    float ps = 0.f;
#pragma unroll
    for (int fc = 0; fc < 4; ++fc) {
      f16x4 pv;
#pragma unroll
      for (int rg = 0; rg < 4; ++rg) {
        float pe = exp2f(s[fc][rg] - mn);
        ps += pe;
        pv[rg] = (f16)pe;
      }
      // P[t][j] row-major (stride 72): elems fc*16 + gq*4 .. +3 of row r
      *(f16x4*)((char*)&lP[w][0] + r * 144 + fc * 32 + gq * 8) = pv;
    }
    ps += __shfl_xor(ps, 16);
    ps += __shfl_xor(ps, 32);
    l += ps;
    f16x8 pf[2];
#pragma unroll
    for (int ks = 0; ks < 2; ++ks)
      pf[ks] = *(const f16x8*)((const char*)&lP[w][0] + r * 144 + ks * 64 + gq * 16);
#pragma unroll
    for (int fd = 0; fd < 4; ++fd)
#pragma unroll
      for (int ks = 0; ks < 2; ++ks)
        O[fd] = __builtin_amdgcn_mfma_f32_16x16x32_f16(vf[fd][ks], pf[ks], O[fd], 0, 0, 0);
  };

  int nkv = 32 - p;
  stage(0, 0);
  int cur = 0;
  for (int kv = 0; kv < nkv; ++kv) {
    int j0 = kv * 64;
    __syncthreads();
    if (kv + 1 < nkv) stage(cur ^ 1, kv + 1);
    const char* bK = (const char*)lK + cur * 8192;
    const char* bV = (const char*)lV + cur * 8192;
    f16x8 kf[4][2];
#pragma unroll
    for (int fc = 0; fc < 4; ++fc)
#pragma unroll
      for (int ks = 0; ks < 2; ++ks) {
        int rj = fc * 16 + r;
        kf[fc][ks] = *(const f16x8*)(bK + rj * 128 + (((ks * 4 + gq) ^ (rj & 7)) * 16));
      }
#pragma unroll
    for (int fd = 0; fd < 4; ++fd)
#pragma unroll
      for (int ks = 0; ks < 2; ++ks) {
        int rd = fd * 16 + r;
        vf[fd][ks] = *(const f16x8*)(bV + rd * 128 + (((ks * 4 + gq) ^ (rd & 7)) * 16));
      }
    // B tile (always active): S^T = K x Q
    f32x4 sB[4] = {};
#pragma unroll
    for (int ks = 0; ks < 2; ++ks)
#pragma unroll
      for (int fc = 0; fc < 4; ++fc)
        sB[fc] = __builtin_amdgcn_mfma_f32_16x16x32_f16(kf[fc][ks], qfB[ks], sB[fc], 0, 0, 0);
    if (kv == nkv - 1) {  // diagonal tile for B
      int t = q0B + r;
#pragma unroll
      for (int fc = 0; fc < 4; ++fc)
#pragma unroll
        for (int rg = 0; rg < 4; ++rg) {
          int j = j0 + fc * 16 + gq * 4 + rg;
          if (j > t) sB[fc][rg] = -1e30f;
        }
    }
    smpv(sB, mB, lB_, OB);
    if (kv <= p) {
      f32x4 sA[4] = {};
#pragma unroll
      for (int ks = 0; ks < 2; ++ks)
#pragma unroll
        for (int fc = 0; fc < 4; ++fc)
          sA[fc] = __builtin_amdgcn_mfma_f32_16x16x32_f16(kf[fc][ks], qfA[ks], sA[fc], 0, 0, 0);
      if (kv == p) {  // diagonal tile for A
        int t = q0A + r;
#pragma unroll
        for (int fc = 0; fc < 4; ++fc)
#pragma unroll
          for (int rg = 0; rg < 4; ++rg) {
            int j = j0 + fc * 16 + gq * 4 + rg;
            if (j > t) sA[fc][rg] = -1e30f;
          }
      }
      smpv(sA, mA, lA_, OA);
    }
    cur ^= 1;
  }
  // O^T: lane holds O[d][t]: t = q0 + r, d = fd*16 + gq*4 + rg
  int bb = bh >> 3, hh = bh & 7;
  auto wout = [&](int q0, f32x4 (&O)[4], float l) {
    float inv = 1.f / l;
    int t = q0 + r;
    f16* o = out + ((size_t)bb * 2048 + t) * 512 + hh * 64 + gq * 4;
#pragma unroll
    for (int fd = 0; fd < 4; ++fd) {
      f16x4 v;
#pragma unroll
      for (int rg = 0; rg < 4; ++rg) v[rg] = (f16)(O[fd][rg] * inv);
      *(f16x4*)(o + fd * 16) = v;
    }
  };
  wout(q0A, OA, lA_);
  wout(q0B, OB, lB_);
}

extern "C" void kernel_launch(void* const* d_in, const int* in_sizes, int n_in,
                              void* d_out, int out_size, void* d_ws, size_t ws_size,
                              hipStream_t stream) {
  (void)in_sizes; (void)n_in; (void)out_size; (void)ws_size;
  const float* x      = (const float*)d_in[0];
  const float* wq     = (const float*)d_in[1];
  const float* wk     = (const float*)d_in[2];
  const float* wv     = (const float*)d_in[3];
  const float* w_proj = (const float*)d_in[4];
  const float* b_proj = (const float*)d_in[5];
  const float* w1     = (const float*)d_in[6];
  const float* b1     = (const float*)d_in[7];
  const float* w2     = (const float*)d_in[8];
  const float* b2     = (const float*)d_in[9];
  const float* g1     = (const float*)d_in[10];
  const float* be1    = (const float*)d_in[11];
  const float* g2     = (const float*)d_in[12];
  const float* be2    = (const float*)d_in[13];
  float* outp = (float*)d_out;

  char* ws = (char*)d_ws;
  size_t off = 0;
  auto alloc = [&](size_t bytes) {
    char* p = ws + off;
    off += (bytes + 255) & ~(size_t)255;
    return p;
  };
  const size_t MC2 = (size_t)8192 * 512 * 2;   // 8.4 MB
  f16* x_ln  = (f16*)alloc(MC2);
  f16* qb    = (f16*)alloc(MC2);   // qb..attn (33.6 MB) reused as hbuf later
  f16* kb    = (f16*)alloc(MC2);
  f16* vb    = (f16*)alloc(MC2);
  f16* attn  = (f16*)alloc(MC2);
  float* x1  = (float*)alloc((size_t)8192 * 512 * 4);
  f16* Wqkv  = (f16*)alloc((size_t)1536 * 512 * 2);
  f16* Wp    = (f16*)alloc((size_t)512 * 512 * 2);
  f16* W1t   = (f16*)alloc((size_t)2048 * 512 * 2);
  f16* W2t   = (f16*)alloc((size_t)512 * 2048 * 2);
  f16* x1_ln = x_ln;
  f16* hbuf  = qb;  // 32 MB spans qb..attn

  // weights -> f16, transposed to [N][K]; scales folded (q gets 512^-0.5 * log2e)
  transpose_cvt<<<dim3(2, 16, 8), 256, 0, stream>>>(wq, Wqkv,                 512, 64, 512 * 64, 64 * 512, kScaleQ);
  transpose_cvt<<<dim3(2, 16, 8), 256, 0, stream>>>(wk, Wqkv + 512 * 512,     512, 64, 512 * 64, 64 * 512, kScale);
  transpose_cvt<<<dim3(2, 16, 8), 256, 0, stream>>>(wv, Wqkv + 2 * 512 * 512, 512, 64, 512 * 64, 64 * 512, kScale);
  transpose_cvt<<<dim3(16, 16, 1), 256, 0, stream>>>(w_proj, Wp, 512, 512, 0, 0, 1.f);
  transpose_cvt<<<dim3(64, 16, 1), 256, 0, stream>>>(w1, W1t, 512, 2048, 0, 0, 1.f);
  transpose_cvt<<<dim3(16, 64, 1), 256, 0, stream>>>(w2, W2t, 2048, 512, 0, 0, kScale);

  ln_kernel<<<2048, 256, 0, stream>>>(x, g1, be1, x_ln);
  gemm_bt<0, false><<<dim3(64, 12), 256, 0, stream>>>(x_ln, Wqkv, nullptr, nullptr, nullptr, nullptr,
                                                      qb, kb, vb, 1536, 512);
  attn_kernel<<<dim3(32, 16), 256, 0, stream>>>(qb, kb, vb, attn);
  gemm_bt<1, true><<<dim3(64, 4), 512, 0, stream>>>(attn, Wp, b_proj, x, x1, nullptr,
                                                    nullptr, nullptr, nullptr, 512, 512);
  ln_kernel<<<2048, 256, 0, stream>>>(x1, g2, be2, x1_ln);
  gemm_bt<2, false><<<dim3(64, 16), 256, 0, stream>>>(x1_ln, W1t, b1, nullptr, nullptr, hbuf,
                                                      nullptr, nullptr, nullptr, 2048, 512);
  gemm_bt<3, true><<<dim3(64, 4), 512, 0, stream>>>(hbuf, W2t, b2, x1, outp, nullptr,
                                                    nullptr, nullptr, nullptr, 512, 2048);
}

// Round 10
// 165.931 us; speedup vs baseline: 1.3345x; 1.0839x over previous
//
#include <hip/hip_runtime.h>

typedef _Float16 f16;
typedef f16 f16x4 __attribute__((ext_vector_type(4)));
typedef f16 f16x8 __attribute__((ext_vector_type(8)));
typedef float f32x4 __attribute__((ext_vector_type(4)));

#define AS1 __attribute__((address_space(1)))
#define AS3 __attribute__((address_space(3)))

constexpr float kScale  = 7.896444077714954f;                       // 6 * 3^0.25
// q scale: SCALE / sqrt(512) * log2(e)  (scores produced directly in log2 units)
constexpr float kScaleQ = (float)(7.896444077714954 / 22.627416997969522 * 1.4426950408889634);

__device__ __forceinline__ void g2l16(const void* g, void* l) {
  __builtin_amdgcn_global_load_lds((const AS1 void*)g, (AS3 void*)l, 16, 0, 0);
}

// ---------------- LayerNorm row quad: fp32 [rows,512] -> f16 ----------------
__device__ __forceinline__ void ln_body(
    const float* __restrict__ x, const float* __restrict__ g,
    const float* __restrict__ be, f16* __restrict__ out, int rowblk) {
  int row = rowblk * 4 + ((int)threadIdx.x >> 6);
  int lane = threadIdx.x & 63;
  const float* xr = x + (size_t)row * 512;
  float xa[8];
  *(float4*)&xa[0] = *(const float4*)(xr + lane * 8);
  *(float4*)&xa[4] = *(const float4*)(xr + lane * 8 + 4);
  float s = 0.f, q = 0.f;
#pragma unroll
  for (int i = 0; i < 8; ++i) { s += xa[i]; q += xa[i] * xa[i]; }
#pragma unroll
  for (int off = 32; off; off >>= 1) { s += __shfl_xor(s, off); q += __shfl_xor(q, off); }
  float mean = s * (1.f / 512.f);
  float var = q * (1.f / 512.f) - mean * mean;
  float rstd = rsqrtf(var + 1e-5f);
  float ga[8], ba[8];
  *(float4*)&ga[0] = *(const float4*)(g + lane * 8);
  *(float4*)&ga[4] = *(const float4*)(g + lane * 8 + 4);
  *(float4*)&ba[0] = *(const float4*)(be + lane * 8);
  *(float4*)&ba[4] = *(const float4*)(be + lane * 8 + 4);
  f16x8 o;
#pragma unroll
  for (int i = 0; i < 8; ++i) o[i] = (f16)((xa[i] - mean) * rstd * ga[i] + ba[i]);
  *(f16x8*)(out + (size_t)row * 512 + lane * 8) = o;
}

__global__ __launch_bounds__(256) void ln_kernel(
    const float* __restrict__ x, const float* __restrict__ g,
    const float* __restrict__ be, f16* __restrict__ out) {
  ln_body(x, g, be, out, blockIdx.x);
}

// ---- fused preprocessing: all 6 weight transposes (+scale,+f16) and LN1 ----
// blocks 0..767: wq/wk/wv (each 2x16x8=256); 768..1023: w_proj (16x16);
// 1024..2047: w1 (64x16); 2048..3071: w2 (16x64); 3072..5119: LN1 (2048).
__global__ __launch_bounds__(256) void preproc_kernel(
    const float* __restrict__ wq, const float* __restrict__ wk,
    const float* __restrict__ wv, const float* __restrict__ wp,
    const float* __restrict__ w1, const float* __restrict__ w2,
    const float* __restrict__ x, const float* __restrict__ g1,
    const float* __restrict__ be1,
    f16* __restrict__ Wqkv, f16* __restrict__ Wp, f16* __restrict__ W1t,
    f16* __restrict__ W2t, f16* __restrict__ x_ln) {
  int bid = blockIdx.x;
  if (bid >= 3072) { ln_body(x, g1, be1, x_ln, bid - 3072); return; }
  __shared__ float t[32][33];
  const float* in; f16* out; int R, Cc, bx, by, bz = 0; float scale;
  if (bid < 768) {
    int which = bid >> 8, rem = bid & 255;
    bx = rem & 1; by = (rem >> 1) & 15; bz = rem >> 5;
    in = which == 0 ? wq : (which == 1 ? wk : wv);
    out = Wqkv + (size_t)which * 512 * 512;
    R = 512; Cc = 64; scale = which == 0 ? kScaleQ : kScale;
  } else if (bid < 1024) {
    int rem = bid - 768; bx = rem & 15; by = rem >> 4;
    in = wp; out = Wp; R = 512; Cc = 512; scale = 1.f;
  } else if (bid < 2048) {
    int rem = bid - 1024; bx = rem & 63; by = rem >> 6;
    in = w1; out = W1t; R = 512; Cc = 2048; scale = 1.f;
  } else {
    int rem = bid - 2048; bx = rem & 15; by = rem >> 4;
    in = w2; out = W2t; R = 2048; Cc = 512; scale = kScale;
  }
  const float* im = in + (size_t)bz * R * Cc;
  f16* om = out + (size_t)bz * Cc * R;
  int c0 = bx * 32, r0 = by * 32;
  int tx = threadIdx.x & 31, ty = threadIdx.x >> 5;
#pragma unroll
  for (int i = 0; i < 4; ++i) {
    int rr = ty + i * 8;
    t[rr][tx] = im[(size_t)(r0 + rr) * Cc + c0 + tx] * scale;
  }
  __syncthreads();
#pragma unroll
  for (int i = 0; i < 4; ++i) {
    int rr = ty + i * 8;
    om[(size_t)(c0 + rr) * R + r0 + tx] = (f16)t[tx][rr];
  }
}

// ------------- GEMM: C[M,N] = A[M,K] * Bt[N,K]^T, f16 in, fp32 acc -------------
// Double-buffered LDS, single barrier per K-step. W8: 512-thread blocks (8 waves,
// 2x4 wave grid, 64x32 per wave) for small-grid cases; else 256-thread (2x2 waves).
// MODE 0: qkv scatter (q,k -> [B,H,T,64]; v -> [B,H,D,T])
// MODE 1: out fp32 = acc + bias + res
// MODE 2: out f16  = relu(acc + bias)
// MODE 3: out fp32 = acc + bias*kScale + res
template <int MODE, bool W8>
__global__ __launch_bounds__(W8 ? 512 : 256) void gemm_bt(
    const f16* __restrict__ A, const f16* __restrict__ Bt,
    const float* __restrict__ bias, const float* __restrict__ res,
    float* __restrict__ outf, f16* __restrict__ outb,
    f16* __restrict__ qo, f16* __restrict__ ko, f16* __restrict__ vo,
    int N, int K) {
  __shared__ f16 lA[2][128 * 64], lB[2][128 * 64];
  constexpr int NF = W8 ? 2 : 4;          // N-fragments per wave
  constexpr int WCW = W8 ? 32 : 64;       // wave col width
  int tid = threadIdx.x;
  int lane = tid & 63, w = tid >> 6;
  int wr = W8 ? (w >> 2) : (w >> 1);
  int wc = W8 ? (w & 3) : (w & 1);
  int gq = lane >> 4, r = lane & 15;
  int m0 = blockIdx.x * 128, n0 = blockIdx.y * 128;
  size_t Kb = (size_t)K * 2;
  const char* Ab = (const char*)A + (size_t)m0 * Kb;
  const char* Bb = (const char*)Bt + (size_t)n0 * Kb;
  f32x4 acc[4][NF] = {};
  int srow = lane >> 3, sslot = lane & 7;
  auto stage = [&](int buf, int kt) {
#pragma unroll
    for (int i = 0; i < (W8 ? 2 : 4); ++i) {
      int chunk = i * (W8 ? 8 : 4) + w;
      int row = chunk * 8 + srow;
      int slot = sslot ^ (row & 7);
      g2l16(Ab + (size_t)row * Kb + kt * 2 + slot * 16, (char*)lA + buf * 16384 + chunk * 1024);
      g2l16(Bb + (size_t)row * Kb + kt * 2 + slot * 16, (char*)lB + buf * 16384 + chunk * 1024);
    }
  };
  stage(0, 0);
  int cur = 0;
  for (int kt = 0; kt < K; kt += 64) {
    __syncthreads();
    if (kt + 64 < K) stage(cur ^ 1, kt + 64);
    const char* bA = (const char*)lA + cur * 16384;
    const char* bB = (const char*)lB + cur * 16384;
    f16x8 af[4][2], bfr[NF][2];
#pragma unroll
    for (int f = 0; f < 4; ++f)
#pragma unroll
      for (int ks = 0; ks < 2; ++ks) {
        int ra = wr * 64 + f * 16 + r;
        af[f][ks] = *(const f16x8*)(bA + ra * 128 + (((ks * 4 + gq) ^ (ra & 7)) * 16));
      }
#pragma unroll
    for (int fn = 0; fn < NF; ++fn)
#pragma unroll
      for (int ks = 0; ks < 2; ++ks) {
        int rb = wc * WCW + fn * 16 + r;
        bfr[fn][ks] = *(const f16x8*)(bB + rb * 128 + (((ks * 4 + gq) ^ (rb & 7)) * 16));
      }
    __builtin_amdgcn_s_setprio(1);
#pragma unroll
    for (int fm = 0; fm < 4; ++fm)
#pragma unroll
      for (int fn = 0; fn < NF; ++fn)
#pragma unroll
        for (int ks = 0; ks < 2; ++ks)
          acc[fm][fn] = __builtin_amdgcn_mfma_f32_16x16x32_f16(af[fm][ks], bfr[fn][ks], acc[fm][fn], 0, 0, 0);
    __builtin_amdgcn_s_setprio(0);
    cur ^= 1;
  }
#pragma unroll
  for (int fm = 0; fm < 4; ++fm)
#pragma unroll
    for (int fn = 0; fn < NF; ++fn)
#pragma unroll
      for (int rg = 0; rg < 4; ++rg) {
        int row = m0 + wr * 64 + fm * 16 + gq * 4 + rg;
        int col = n0 + wc * WCW + fn * 16 + r;
        float v = acc[fm][fn][rg];
        if constexpr (MODE == 1) {
          outf[(size_t)row * N + col] = v + bias[col] + res[(size_t)row * N + col];
        } else if constexpr (MODE == 2) {
          outb[(size_t)row * N + col] = (f16)fmaxf(v + bias[col], 0.f);
        } else if constexpr (MODE == 3) {
          outf[(size_t)row * N + col] = v + bias[col] * kScale + res[(size_t)row * N + col];
        } else {
          int bb = row >> 11, t = row & 2047;
          int which = col >> 9, hd = col & 511, hh = hd >> 6, d = hd & 63;
          size_t bh = (size_t)bb * 8 + hh;
          if (which == 0)      qo[(bh * 2048 + t) * 64 + d] = (f16)v;
          else if (which == 1) ko[(bh * 2048 + t) * 64 + d] = (f16)v;
          else                 vo[(bh * 64 + d) * 2048 + t] = (f16)v;
        }
      }
}

// ------------- causal flash attention, SWAPPED QK^T (lane-local softmax) -------------
// q,k:[B,H,T,64], v^T:[B,H,64,T]. Block (bh,p): 4 waves, tiles A=p and B=31-p
// (16 q-rows per wave per tile). Scores S^T = mfma(K, Q): lane holds 16 j-values
// for ONE q-row t = q0 + (lane&15). Row-sum l computed on the MFMA pipe via a
// ones-fragment: Ol = mfma(ones, P, Ol) -> every lane's Ol[0] = l(t=r).
// PV: O^T = mfma(V^T, P). Scores in log2 units; exp2 softmax; defer-max.
__global__ __launch_bounds__(256) void attn_kernel(
    const f16* __restrict__ Q, const f16* __restrict__ K,
    const f16* __restrict__ Vt, f16* __restrict__ out) {
  __shared__ f16 lK[2][64 * 64], lV[2][64 * 64];
  __shared__ f16 lP[4][16 * 72];
  int tid = threadIdx.x, lane = tid & 63, w = tid >> 6;
  int gq = lane >> 4, r = lane & 15;
  int bh = blockIdx.x;   // 0..31
  int p = blockIdx.y;    // 0..15 -> tiles p and 31-p
  const char* Qb = (const char*)(Q + (size_t)bh * 2048 * 64);
  const char* Kb = (const char*)(K + (size_t)bh * 2048 * 64);
  const char* Vb = (const char*)(Vt + (size_t)bh * 64 * 2048);
  int q0A = p * 64 + w * 16;
  int q0B = (31 - p) * 64 + w * 16;
  f16x8 qfA[2], qfB[2];
#pragma unroll
  for (int ks = 0; ks < 2; ++ks) {
    qfA[ks] = *(const f16x8*)(Qb + (size_t)(q0A + r) * 128 + ks * 64 + gq * 16);
    qfB[ks] = *(const f16x8*)(Qb + (size_t)(q0B + r) * 128 + ks * 64 + gq * 16);
  }
  f16x8 ones;
#pragma unroll
  for (int i = 0; i < 8; ++i) ones[i] = (f16)1.f;
  f32x4 OA[4] = {}, OB[4] = {}, OlA = {}, OlB = {};
  float mA = -1e30f, mB = -1e30f;
  int srow = lane >> 3, sslot = lane & 7;

  auto stage = [&](int buf, int kv) {
    int j0 = kv * 64;
#pragma unroll
    for (int i = 0; i < 2; ++i) {
      int chunk = i * 4 + w;
      int row = chunk * 8 + srow;
      int slot = sslot ^ (row & 7);
      g2l16(Kb + (size_t)(j0 + row) * 128 + slot * 16, (char*)lK + buf * 8192 + chunk * 1024);
      g2l16(Vb + (size_t)row * 4096 + j0 * 2 + slot * 16, (char*)lV + buf * 8192 + chunk * 1024);
    }
  };

  f16x8 vf[4][2];
  // s[fc][rg] holds S^T[j][t]: j = j0 + fc*16 + gq*4 + rg, t = q0 + r
  auto smpv = [&](f32x4 (&s)[4], float& m, f32x4 (&O)[4], f32x4& Ol) {
    float t0 = fmaxf(fmaxf(s[0][0], s[0][1]), fmaxf(s[0][2], s[0][3]));
    float t1 = fmaxf(fmaxf(s[1][0], s[1][1]), fmaxf(s[1][2], s[1][3]));
    float t2 = fmaxf(fmaxf(s[2][0], s[2][1]), fmaxf(s[2][2], s[2][3]));
    float t3 = fmaxf(fmaxf(s[3][0], s[3][1]), fmaxf(s[3][2], s[3][3]));
    float pmax = fmaxf(fmaxf(t0, t1), fmaxf(t2, t3));
    pmax = fmaxf(pmax, __shfl_xor(pmax, 16));
    pmax = fmaxf(pmax, __shfl_xor(pmax, 32));
    float mn = fmaxf(m, pmax);
    if (mn - m > 11.5f) {  // defer-max (log2 units)
      float sc = exp2f(m - mn);
#pragma unroll
      for (int fd = 0; fd < 4; ++fd) O[fd] *= sc;
      Ol *= sc;
      m = mn;
    } else {
      mn = m;
    }
#pragma unroll
    for (int fc = 0; fc < 4; ++fc) {
      f16x4 pv;
#pragma unroll
      for (int rg = 0; rg < 4; ++rg) pv[rg] = (f16)exp2f(s[fc][rg] - mn);
      // P[t][j] row-major (stride 72): elems fc*16 + gq*4 .. +3 of row r
      *(f16x4*)((char*)&lP[w][0] + r * 144 + fc * 32 + gq * 8) = pv;
    }
    f16x8 pf[2];
#pragma unroll
    for (int ks = 0; ks < 2; ++ks)
      pf[ks] = *(const f16x8*)((const char*)&lP[w][0] + r * 144 + ks * 64 + gq * 16);
#pragma unroll
    for (int fd = 0; fd < 4; ++fd)
#pragma unroll
      for (int ks = 0; ks < 2; ++ks)
        O[fd] = __builtin_amdgcn_mfma_f32_16x16x32_f16(vf[fd][ks], pf[ks], O[fd], 0, 0, 0);
#pragma unroll
    for (int ks = 0; ks < 2; ++ks)
      Ol = __builtin_amdgcn_mfma_f32_16x16x32_f16(ones, pf[ks], Ol, 0, 0, 0);
  };

  int nkv = 32 - p;
  stage(0, 0);
  int cur = 0;
  for (int kv = 0; kv < nkv; ++kv) {
    int j0 = kv * 64;
    __syncthreads();
    if (kv + 1 < nkv) stage(cur ^ 1, kv + 1);
    const char* bK = (const char*)lK + cur * 8192;
    const char* bV = (const char*)lV + cur * 8192;
    f16x8 kf[4][2];
#pragma unroll
    for (int fc = 0; fc < 4; ++fc)
#pragma unroll
      for (int ks = 0; ks < 2; ++ks) {
        int rj = fc * 16 + r;
        kf[fc][ks] = *(const f16x8*)(bK + rj * 128 + (((ks * 4 + gq) ^ (rj & 7)) * 16));
      }
#pragma unroll
    for (int fd = 0; fd < 4; ++fd)
#pragma unroll
      for (int ks = 0; ks < 2; ++ks) {
        int rd = fd * 16 + r;
        vf[fd][ks] = *(const f16x8*)(bV + rd * 128 + (((ks * 4 + gq) ^ (rd & 7)) * 16));
      }
    // B tile (always active): S^T = K x Q
    f32x4 sB[4] = {};
#pragma unroll
    for (int ks = 0; ks < 2; ++ks)
#pragma unroll
      for (int fc = 0; fc < 4; ++fc)
        sB[fc] = __builtin_amdgcn_mfma_f32_16x16x32_f16(kf[fc][ks], qfB[ks], sB[fc], 0, 0, 0);
    if (kv == nkv - 1) {  // diagonal tile for B
      int t = q0B + r;
#pragma unroll
      for (int fc = 0; fc < 4; ++fc)
#pragma unroll
        for (int rg = 0; rg < 4; ++rg) {
          int j = j0 + fc * 16 + gq * 4 + rg;
          if (j > t) sB[fc][rg] = -1e30f;
        }
    }
    smpv(sB, mB, OB, OlB);
    if (kv <= p) {
      f32x4 sA[4] = {};
#pragma unroll
      for (int ks = 0; ks < 2; ++ks)
#pragma unroll
        for (int fc = 0; fc < 4; ++fc)
          sA[fc] = __builtin_amdgcn_mfma_f32_16x16x32_f16(kf[fc][ks], qfA[ks], sA[fc], 0, 0, 0);
      if (kv == p) {  // diagonal tile for A
        int t = q0A + r;
#pragma unroll
        for (int fc = 0; fc < 4; ++fc)
#pragma unroll
          for (int rg = 0; rg < 4; ++rg) {
            int j = j0 + fc * 16 + gq * 4 + rg;
            if (j > t) sA[fc][rg] = -1e30f;
          }
      }
      smpv(sA, mA, OA, OlA);
    }
    cur ^= 1;
  }
  // O^T: lane holds O[d][t]: t = q0 + r, d = fd*16 + gq*4 + rg; l = Ol[0]
  int bb = bh >> 3, hh = bh & 7;
  auto wout = [&](int q0, f32x4 (&O)[4], float l) {
    float inv = 1.f / l;
    int t = q0 + r;
    f16* o = out + ((size_t)bb * 2048 + t) * 512 + hh * 64 + gq * 4;
#pragma unroll
    for (int fd = 0; fd < 4; ++fd) {
      f16x4 v;
#pragma unroll
      for (int rg = 0; rg < 4; ++rg) v[rg] = (f16)(O[fd][rg] * inv);
      *(f16x4*)(o + fd * 16) = v;
    }
  };
  wout(q0A, OA, OlA[0]);
  wout(q0B, OB, OlB[0]);
}

extern "C" void kernel_launch(void* const* d_in, const int* in_sizes, int n_in,
                              void* d_out, int out_size, void* d_ws, size_t ws_size,
                              hipStream_t stream) {
  (void)in_sizes; (void)n_in; (void)out_size; (void)ws_size;
  const float* x      = (const float*)d_in[0];
  const float* wq     = (const float*)d_in[1];
  const float* wk     = (const float*)d_in[2];
  const float* wv     = (const float*)d_in[3];
  const float* w_proj = (const float*)d_in[4];
  const float* b_proj = (const float*)d_in[5];
  const float* w1     = (const float*)d_in[6];
  const float* b1     = (const float*)d_in[7];
  const float* w2     = (const float*)d_in[8];
  const float* b2     = (const float*)d_in[9];
  const float* g1     = (const float*)d_in[10];
  const float* be1    = (const float*)d_in[11];
  const float* g2     = (const float*)d_in[12];
  const float* be2    = (const float*)d_in[13];
  float* outp = (float*)d_out;

  char* ws = (char*)d_ws;
  size_t off = 0;
  auto alloc = [&](size_t bytes) {
    char* p = ws + off;
    off += (bytes + 255) & ~(size_t)255;
    return p;
  };
  const size_t MC2 = (size_t)8192 * 512 * 2;   // 8.4 MB
  f16* x_ln  = (f16*)alloc(MC2);
  f16* qb    = (f16*)alloc(MC2);   // qb..attn (33.6 MB) reused as hbuf later
  f16* kb    = (f16*)alloc(MC2);
  f16* vb    = (f16*)alloc(MC2);
  f16* attn  = (f16*)alloc(MC2);
  float* x1  = (float*)alloc((size_t)8192 * 512 * 4);
  f16* Wqkv  = (f16*)alloc((size_t)1536 * 512 * 2);
  f16* Wp    = (f16*)alloc((size_t)512 * 512 * 2);
  f16* W1t   = (f16*)alloc((size_t)2048 * 512 * 2);
  f16* W2t   = (f16*)alloc((size_t)512 * 2048 * 2);
  f16* x1_ln = x_ln;
  f16* hbuf  = qb;  // 32 MB spans qb..attn

  // fused: all weight transposes (scales folded; q gets 512^-0.5 * log2e) + LN1
  preproc_kernel<<<5120, 256, 0, stream>>>(wq, wk, wv, w_proj, w1, w2, x, g1, be1,
                                           Wqkv, Wp, W1t, W2t, x_ln);
  gemm_bt<0, false><<<dim3(64, 12), 256, 0, stream>>>(x_ln, Wqkv, nullptr, nullptr, nullptr, nullptr,
                                                      qb, kb, vb, 1536, 512);
  attn_kernel<<<dim3(32, 16), 256, 0, stream>>>(qb, kb, vb, attn);
  gemm_bt<1, true><<<dim3(64, 4), 512, 0, stream>>>(attn, Wp, b_proj, x, x1, nullptr,
                                                    nullptr, nullptr, nullptr, 512, 512);
  ln_kernel<<<2048, 256, 0, stream>>>(x1, g2, be2, x1_ln);
  gemm_bt<2, false><<<dim3(64, 16), 256, 0, stream>>>(x1_ln, W1t, b1, nullptr, nullptr, hbuf,
                                                      nullptr, nullptr, nullptr, 2048, 512);
  gemm_bt<3, true><<<dim3(64, 4), 512, 0, stream>>>(hbuf, W2t, b2, x1, outp, nullptr,
                                                    nullptr, nullptr, nullptr, 512, 2048);
}

// Round 11
// 163.068 us; speedup vs baseline: 1.3580x; 1.0176x over previous
//
#include <hip/hip_runtime.h>

typedef _Float16 f16;
typedef f16 f16x4 __attribute__((ext_vector_type(4)));
typedef f16 f16x8 __attribute__((ext_vector_type(8)));
typedef float f32x4 __attribute__((ext_vector_type(4)));

#define AS1 __attribute__((address_space(1)))
#define AS3 __attribute__((address_space(3)))

constexpr float kScale  = 7.896444077714954f;                       // 6 * 3^0.25
// q scale: SCALE / sqrt(512) * log2(e)  (scores produced directly in log2 units)
constexpr float kScaleQ = (float)(7.896444077714954 / 22.627416997969522 * 1.4426950408889634);

__device__ __forceinline__ void g2l16(const void* g, void* l) {
  __builtin_amdgcn_global_load_lds((const AS1 void*)g, (AS3 void*)l, 16, 0, 0);
}

// ---------------- LayerNorm row quad: fp32 [rows,512] -> f16 ----------------
__device__ __forceinline__ void ln_body(
    const float* __restrict__ x, const float* __restrict__ g,
    const float* __restrict__ be, f16* __restrict__ out, int rowblk) {
  int row = rowblk * 4 + ((int)threadIdx.x >> 6);
  int lane = threadIdx.x & 63;
  const float* xr = x + (size_t)row * 512;
  float xa[8];
  *(float4*)&xa[0] = *(const float4*)(xr + lane * 8);
  *(float4*)&xa[4] = *(const float4*)(xr + lane * 8 + 4);
  float s = 0.f, q = 0.f;
#pragma unroll
  for (int i = 0; i < 8; ++i) { s += xa[i]; q += xa[i] * xa[i]; }
#pragma unroll
  for (int off = 32; off; off >>= 1) { s += __shfl_xor(s, off); q += __shfl_xor(q, off); }
  float mean = s * (1.f / 512.f);
  float var = q * (1.f / 512.f) - mean * mean;
  float rstd = rsqrtf(var + 1e-5f);
  float ga[8], ba[8];
  *(float4*)&ga[0] = *(const float4*)(g + lane * 8);
  *(float4*)&ga[4] = *(const float4*)(g + lane * 8 + 4);
  *(float4*)&ba[0] = *(const float4*)(be + lane * 8);
  *(float4*)&ba[4] = *(const float4*)(be + lane * 8 + 4);
  f16x8 o;
#pragma unroll
  for (int i = 0; i < 8; ++i) o[i] = (f16)((xa[i] - mean) * rstd * ga[i] + ba[i]);
  *(f16x8*)(out + (size_t)row * 512 + lane * 8) = o;
}

__global__ __launch_bounds__(256) void ln_kernel(
    const float* __restrict__ x, const float* __restrict__ g,
    const float* __restrict__ be, f16* __restrict__ out) {
  ln_body(x, g, be, out, blockIdx.x);
}

// ---- fused preprocessing: all 6 weight transposes (+scale,+f16) and LN1 ----
// blocks 0..767: wq/wk/wv (each 2x16x8=256); 768..1023: w_proj (16x16);
// 1024..2047: w1 (64x16); 2048..3071: w2 (16x64); 3072..5119: LN1 (2048).
__global__ __launch_bounds__(256) void preproc_kernel(
    const float* __restrict__ wq, const float* __restrict__ wk,
    const float* __restrict__ wv, const float* __restrict__ wp,
    const float* __restrict__ w1, const float* __restrict__ w2,
    const float* __restrict__ x, const float* __restrict__ g1,
    const float* __restrict__ be1,
    f16* __restrict__ Wqkv, f16* __restrict__ Wp, f16* __restrict__ W1t,
    f16* __restrict__ W2t, f16* __restrict__ x_ln) {
  int bid = blockIdx.x;
  if (bid >= 3072) { ln_body(x, g1, be1, x_ln, bid - 3072); return; }
  __shared__ float t[32][33];
  const float* in; f16* out; int R, Cc, bx, by, bz = 0; float scale;
  if (bid < 768) {
    int which = bid >> 8, rem = bid & 255;
    bx = rem & 1; by = (rem >> 1) & 15; bz = rem >> 5;
    in = which == 0 ? wq : (which == 1 ? wk : wv);
    out = Wqkv + (size_t)which * 512 * 512;
    R = 512; Cc = 64; scale = which == 0 ? kScaleQ : kScale;
  } else if (bid < 1024) {
    int rem = bid - 768; bx = rem & 15; by = rem >> 4;
    in = wp; out = Wp; R = 512; Cc = 512; scale = 1.f;
  } else if (bid < 2048) {
    int rem = bid - 1024; bx = rem & 63; by = rem >> 6;
    in = w1; out = W1t; R = 512; Cc = 2048; scale = 1.f;
  } else {
    int rem = bid - 2048; bx = rem & 15; by = rem >> 4;
    in = w2; out = W2t; R = 2048; Cc = 512; scale = kScale;
  }
  const float* im = in + (size_t)bz * R * Cc;
  f16* om = out + (size_t)bz * Cc * R;
  int c0 = bx * 32, r0 = by * 32;
  int tx = threadIdx.x & 31, ty = threadIdx.x >> 5;
#pragma unroll
  for (int i = 0; i < 4; ++i) {
    int rr = ty + i * 8;
    t[rr][tx] = im[(size_t)(r0 + rr) * Cc + c0 + tx] * scale;
  }
  __syncthreads();
#pragma unroll
  for (int i = 0; i < 4; ++i) {
    int rr = ty + i * 8;
    om[(size_t)(c0 + rr) * R + r0 + tx] = (f16)t[tx][rr];
  }
}

// ------------- GEMM: C[M,N] = A[M,K] * Bt[N,K]^T, f16 in, fp32 acc -------------
// Double-buffered LDS, single barrier per K-step. W8: 512-thread blocks (8 waves,
// 2x4 wave grid, 64x32 per wave) for small-grid cases; else 256-thread (2x2 waves).
// MODE 0: qkv scatter (q,k -> [B,H,T,64]; v -> [B,H,D,T])
// MODE 1: out fp32 = acc + bias + res
// MODE 2: out f16  = relu(acc + bias)
// MODE 3: out fp32 = acc + bias*kScale + res
template <int MODE, bool W8>
__global__ __launch_bounds__(W8 ? 512 : 256) void gemm_bt(
    const f16* __restrict__ A, const f16* __restrict__ Bt,
    const float* __restrict__ bias, const float* __restrict__ res,
    float* __restrict__ outf, f16* __restrict__ outb,
    f16* __restrict__ qo, f16* __restrict__ ko, f16* __restrict__ vo,
    int N, int K) {
  __shared__ f16 lA[2][128 * 64], lB[2][128 * 64];
  constexpr int NF = W8 ? 2 : 4;          // N-fragments per wave
  constexpr int WCW = W8 ? 32 : 64;       // wave col width
  int tid = threadIdx.x;
  int lane = tid & 63, w = tid >> 6;
  int wr = W8 ? (w >> 2) : (w >> 1);
  int wc = W8 ? (w & 3) : (w & 1);
  int gq = lane >> 4, r = lane & 15;
  int m0 = blockIdx.x * 128, n0 = blockIdx.y * 128;
  size_t Kb = (size_t)K * 2;
  const char* Ab = (const char*)A + (size_t)m0 * Kb;
  const char* Bb = (const char*)Bt + (size_t)n0 * Kb;
  f32x4 acc[4][NF] = {};
  int srow = lane >> 3, sslot = lane & 7;
  auto stage = [&](int buf, int kt) {
#pragma unroll
    for (int i = 0; i < (W8 ? 2 : 4); ++i) {
      int chunk = i * (W8 ? 8 : 4) + w;
      int row = chunk * 8 + srow;
      int slot = sslot ^ (row & 7);
      g2l16(Ab + (size_t)row * Kb + kt * 2 + slot * 16, (char*)lA + buf * 16384 + chunk * 1024);
      g2l16(Bb + (size_t)row * Kb + kt * 2 + slot * 16, (char*)lB + buf * 16384 + chunk * 1024);
    }
  };
  stage(0, 0);
  int cur = 0;
  for (int kt = 0; kt < K; kt += 64) {
    __syncthreads();
    if (kt + 64 < K) stage(cur ^ 1, kt + 64);
    const char* bA = (const char*)lA + cur * 16384;
    const char* bB = (const char*)lB + cur * 16384;
    f16x8 af[4][2], bfr[NF][2];
#pragma unroll
    for (int f = 0; f < 4; ++f)
#pragma unroll
      for (int ks = 0; ks < 2; ++ks) {
        int ra = wr * 64 + f * 16 + r;
        af[f][ks] = *(const f16x8*)(bA + ra * 128 + (((ks * 4 + gq) ^ (ra & 7)) * 16));
      }
#pragma unroll
    for (int fn = 0; fn < NF; ++fn)
#pragma unroll
      for (int ks = 0; ks < 2; ++ks) {
        int rb = wc * WCW + fn * 16 + r;
        bfr[fn][ks] = *(const f16x8*)(bB + rb * 128 + (((ks * 4 + gq) ^ (rb & 7)) * 16));
      }
    __builtin_amdgcn_s_setprio(1);
#pragma unroll
    for (int fm = 0; fm < 4; ++fm)
#pragma unroll
      for (int fn = 0; fn < NF; ++fn)
#pragma unroll
        for (int ks = 0; ks < 2; ++ks)
          acc[fm][fn] = __builtin_amdgcn_mfma_f32_16x16x32_f16(af[fm][ks], bfr[fn][ks], acc[fm][fn], 0, 0, 0);
    __builtin_amdgcn_s_setprio(0);
    cur ^= 1;
  }
#pragma unroll
  for (int fm = 0; fm < 4; ++fm)
#pragma unroll
    for (int fn = 0; fn < NF; ++fn)
#pragma unroll
      for (int rg = 0; rg < 4; ++rg) {
        int row = m0 + wr * 64 + fm * 16 + gq * 4 + rg;
        int col = n0 + wc * WCW + fn * 16 + r;
        float v = acc[fm][fn][rg];
        if constexpr (MODE == 1) {
          outf[(size_t)row * N + col] = v + bias[col] + res[(size_t)row * N + col];
        } else if constexpr (MODE == 2) {
          outb[(size_t)row * N + col] = (f16)fmaxf(v + bias[col], 0.f);
        } else if constexpr (MODE == 3) {
          outf[(size_t)row * N + col] = v + bias[col] * kScale + res[(size_t)row * N + col];
        } else {
          int bb = row >> 11, t = row & 2047;
          int which = col >> 9, hd = col & 511, hh = hd >> 6, d = hd & 63;
          size_t bh = (size_t)bb * 8 + hh;
          if (which == 0)      qo[(bh * 2048 + t) * 64 + d] = (f16)v;
          else if (which == 1) ko[(bh * 2048 + t) * 64 + d] = (f16)v;
          else                 vo[(bh * 64 + d) * 2048 + t] = (f16)v;
        }
      }
}

// ------------- causal flash attention, SWAPPED QK^T, un-paired tiles -------------
// q,k:[B,H,T,64], v^T:[B,H,64,T]. Block (bh, y): q-tile qt = 31-y (heavy first),
// 4 waves x 16 q-rows. Scores S^T = mfma(K, Q): lane holds 16 j-values for ONE
// q-row t = q0 + (lane&15) -> lane-local row max + 2 shuffles. Row-sum l on the
// MFMA pipe via ones-fragment. PV: O^T = mfma(V^T, P). log2-domain, defer-max.
__global__ __launch_bounds__(256) void attn_kernel(
    const f16* __restrict__ Q, const f16* __restrict__ K,
    const f16* __restrict__ Vt, f16* __restrict__ out) {
  __shared__ f16 lK[2][64 * 64], lV[2][64 * 64];
  __shared__ f16 lP[4][16 * 72];
  int tid = threadIdx.x, lane = tid & 63, w = tid >> 6;
  int gq = lane >> 4, r = lane & 15;
  int bh = blockIdx.x;          // 0..31
  int qt = 31 - (int)blockIdx.y; // heavy tiles dispatched first
  const char* Qb = (const char*)(Q + (size_t)bh * 2048 * 64);
  const char* Kb = (const char*)(K + (size_t)bh * 2048 * 64);
  const char* Vb = (const char*)(Vt + (size_t)bh * 64 * 2048);
  int q0 = qt * 64 + w * 16;
  f16x8 qf[2];
#pragma unroll
  for (int ks = 0; ks < 2; ++ks)
    qf[ks] = *(const f16x8*)(Qb + (size_t)(q0 + r) * 128 + ks * 64 + gq * 16);
  f16x8 ones;
#pragma unroll
  for (int i = 0; i < 8; ++i) ones[i] = (f16)1.f;
  f32x4 O[4] = {}, Ol = {};
  float m = -1e30f;
  int srow = lane >> 3, sslot = lane & 7;

  auto stage = [&](int buf, int kv) {
    int j0 = kv * 64;
#pragma unroll
    for (int i = 0; i < 2; ++i) {
      int chunk = i * 4 + w;
      int row = chunk * 8 + srow;
      int slot = sslot ^ (row & 7);
      g2l16(Kb + (size_t)(j0 + row) * 128 + slot * 16, (char*)lK + buf * 8192 + chunk * 1024);
      g2l16(Vb + (size_t)row * 4096 + j0 * 2 + slot * 16, (char*)lV + buf * 8192 + chunk * 1024);
    }
  };

  int nkv = qt + 1;
  stage(0, 0);
  int cur = 0;
  for (int kv = 0; kv < nkv; ++kv) {
    int j0 = kv * 64;
    __syncthreads();
    if (kv + 1 < nkv) stage(cur ^ 1, kv + 1);
    const char* bK = (const char*)lK + cur * 8192;
    const char* bV = (const char*)lV + cur * 8192;
    f16x8 kf[4][2], vf[4][2];
#pragma unroll
    for (int fc = 0; fc < 4; ++fc)
#pragma unroll
      for (int ks = 0; ks < 2; ++ks) {
        int rj = fc * 16 + r;
        int off = rj * 128 + (((ks * 4 + gq) ^ (rj & 7)) * 16);
        kf[fc][ks] = *(const f16x8*)(bK + off);
        vf[fc][ks] = *(const f16x8*)(bV + off);
      }
    // S^T = K x Q: s[fc][rg] = S[j0+fc*16+gq*4+rg][q0+r]
    f32x4 s[4] = {};
#pragma unroll
    for (int ks = 0; ks < 2; ++ks)
#pragma unroll
      for (int fc = 0; fc < 4; ++fc)
        s[fc] = __builtin_amdgcn_mfma_f32_16x16x32_f16(kf[fc][ks], qf[ks], s[fc], 0, 0, 0);
    if (kv == qt) {  // diagonal tile
      int t = q0 + r;
#pragma unroll
      for (int fc = 0; fc < 4; ++fc)
#pragma unroll
        for (int rg = 0; rg < 4; ++rg) {
          int j = j0 + fc * 16 + gq * 4 + rg;
          if (j > t) s[fc][rg] = -1e30f;
        }
    }
    // softmax (lane-local row) + PV
    float t0 = fmaxf(fmaxf(s[0][0], s[0][1]), fmaxf(s[0][2], s[0][3]));
    float t1 = fmaxf(fmaxf(s[1][0], s[1][1]), fmaxf(s[1][2], s[1][3]));
    float t2 = fmaxf(fmaxf(s[2][0], s[2][1]), fmaxf(s[2][2], s[2][3]));
    float t3 = fmaxf(fmaxf(s[3][0], s[3][1]), fmaxf(s[3][2], s[3][3]));
    float pmax = fmaxf(fmaxf(t0, t1), fmaxf(t2, t3));
    pmax = fmaxf(pmax, __shfl_xor(pmax, 16));
    pmax = fmaxf(pmax, __shfl_xor(pmax, 32));
    float mn = fmaxf(m, pmax);
    if (mn - m > 11.5f) {  // defer-max (log2 units)
      float sc = exp2f(m - mn);
#pragma unroll
      for (int fd = 0; fd < 4; ++fd) O[fd] *= sc;
      Ol *= sc;
      m = mn;
    } else {
      mn = m;
    }
#pragma unroll
    for (int fc = 0; fc < 4; ++fc) {
      f16x4 pv;
#pragma unroll
      for (int rg = 0; rg < 4; ++rg) pv[rg] = (f16)exp2f(s[fc][rg] - mn);
      *(f16x4*)((char*)&lP[w][0] + r * 144 + fc * 32 + gq * 8) = pv;
    }
    f16x8 pf[2];
#pragma unroll
    for (int ks = 0; ks < 2; ++ks)
      pf[ks] = *(const f16x8*)((const char*)&lP[w][0] + r * 144 + ks * 64 + gq * 16);
#pragma unroll
    for (int fd = 0; fd < 4; ++fd)
#pragma unroll
      for (int ks = 0; ks < 2; ++ks)
        O[fd] = __builtin_amdgcn_mfma_f32_16x16x32_f16(vf[fd][ks], pf[ks], O[fd], 0, 0, 0);
#pragma unroll
    for (int ks = 0; ks < 2; ++ks)
      Ol = __builtin_amdgcn_mfma_f32_16x16x32_f16(ones, pf[ks], Ol, 0, 0, 0);
    cur ^= 1;
  }
  // O^T: lane holds O[d][t]: t = q0 + r, d = fd*16 + gq*4 + rg; l = Ol[0]
  int bb = bh >> 3, hh = bh & 7;
  float inv = 1.f / Ol[0];
  int t = q0 + r;
  f16* o = out + ((size_t)bb * 2048 + t) * 512 + hh * 64 + gq * 4;
#pragma unroll
  for (int fd = 0; fd < 4; ++fd) {
    f16x4 v;
#pragma unroll
    for (int rg = 0; rg < 4; ++rg) v[rg] = (f16)(O[fd][rg] * inv);
    *(f16x4*)(o + fd * 16) = v;
  }
}

extern "C" void kernel_launch(void* const* d_in, const int* in_sizes, int n_in,
                              void* d_out, int out_size, void* d_ws, size_t ws_size,
                              hipStream_t stream) {
  (void)in_sizes; (void)n_in; (void)out_size; (void)ws_size;
  const float* x      = (const float*)d_in[0];
  const float* wq     = (const float*)d_in[1];
  const float* wk     = (const float*)d_in[2];
  const float* wv     = (const float*)d_in[3];
  const float* w_proj = (const float*)d_in[4];
  const float* b_proj = (const float*)d_in[5];
  const float* w1     = (const float*)d_in[6];
  const float* b1     = (const float*)d_in[7];
  const float* w2     = (const float*)d_in[8];
  const float* b2     = (const float*)d_in[9];
  const float* g1     = (const float*)d_in[10];
  const float* be1    = (const float*)d_in[11];
  const float* g2     = (const float*)d_in[12];
  const float* be2    = (const float*)d_in[13];
  float* outp = (float*)d_out;

  char* ws = (char*)d_ws;
  size_t off = 0;
  auto alloc = [&](size_t bytes) {
    char* p = ws + off;
    off += (bytes + 255) & ~(size_t)255;
    return p;
  };
  const size_t MC2 = (size_t)8192 * 512 * 2;   // 8.4 MB
  f16* x_ln  = (f16*)alloc(MC2);
  f16* qb    = (f16*)alloc(MC2);   // qb..attn (33.6 MB) reused as hbuf later
  f16* kb    = (f16*)alloc(MC2);
  f16* vb    = (f16*)alloc(MC2);
  f16* attn  = (f16*)alloc(MC2);
  float* x1  = (float*)alloc((size_t)8192 * 512 * 4);
  f16* Wqkv  = (f16*)alloc((size_t)1536 * 512 * 2);
  f16* Wp    = (f16*)alloc((size_t)512 * 512 * 2);
  f16* W1t   = (f16*)alloc((size_t)2048 * 512 * 2);
  f16* W2t   = (f16*)alloc((size_t)512 * 2048 * 2);
  f16* x1_ln = x_ln;
  f16* hbuf  = qb;  // 32 MB spans qb..attn

  // fused: all weight transposes (scales folded; q gets 512^-0.5 * log2e) + LN1
  preproc_kernel<<<5120, 256, 0, stream>>>(wq, wk, wv, w_proj, w1, w2, x, g1, be1,
                                           Wqkv, Wp, W1t, W2t, x_ln);
  gemm_bt<0, false><<<dim3(64, 12), 256, 0, stream>>>(x_ln, Wqkv, nullptr, nullptr, nullptr, nullptr,
                                                      qb, kb, vb, 1536, 512);
  attn_kernel<<<dim3(32, 32), 256, 0, stream>>>(qb, kb, vb, attn);
  gemm_bt<1, true><<<dim3(64, 4), 512, 0, stream>>>(attn, Wp, b_proj, x, x1, nullptr,
                                                    nullptr, nullptr, nullptr, 512, 512);
  ln_kernel<<<2048, 256, 0, stream>>>(x1, g2, be2, x1_ln);
  gemm_bt<2, false><<<dim3(64, 16), 256, 0, stream>>>(x1_ln, W1t, b1, nullptr, nullptr, hbuf,
                                                      nullptr, nullptr, nullptr, 2048, 512);
  gemm_bt<3, true><<<dim3(64, 4), 512, 0, stream>>>(hbuf, W2t, b2, x1, outp, nullptr,
                                                    nullptr, nullptr, nullptr, 512, 2048);
}